// Round 1
// baseline (1840.071 us; speedup 1.0000x reference)
//
#include <hip/hip_runtime.h>
#include <math.h>

constexpr int B_ = 8;
constexpr int N_ = 1024;
constexpr int K_ = 20;
constexpr float EPS_ = 1e-5f;

// ---------------------------------------------------------------- sq kernel
__global__ __launch_bounds__(256) void sq_kernel(const float* __restrict__ x,
                                                 float* __restrict__ sq, int C) {
    int t = blockIdx.x * 256 + threadIdx.x;
    if (t >= B_ * N_) return;
    const float* r = x + (size_t)t * C;
    float s = 0.f;
    for (int c = 0; c < C; ++c) s += r[c] * r[c];
    sq[t] = s;
}

// ---------------------------------------------------------------- knn kernel
// One block handles 8 rows of one batch: computes dist row (1024) into LDS,
// then each wave selects top-20 for 2 rows via iterative argmax in registers.
template <int CIN>
__global__ __launch_bounds__(256) void knn_kernel(const float* __restrict__ x,
                                                  const float* __restrict__ sq,
                                                  int* __restrict__ idx) {
    constexpr int ROWS = 8;
    __shared__ float dist[ROWS][N_];
    __shared__ float ctr[ROWS][CIN];
    int t = threadIdx.x;
    int bb = blockIdx.x / (N_ / ROWS);
    int r0 = (blockIdx.x % (N_ / ROWS)) * ROWS;
    const float* xb = x + (size_t)bb * N_ * CIN;
    const float* sqb = sq + bb * N_;

    for (int e = t; e < ROWS * CIN; e += 256)
        ctr[e / CIN][e % CIN] = xb[(size_t)(r0 + e / CIN) * CIN + e % CIN];
    __syncthreads();

    {   // distances: 8 rows x 32 col-groups
        int r = t >> 5, cg = t & 31;
        float sqr = sqb[r0 + r];
        for (int j = 0; j < N_ / 32; ++j) {
            int m = cg + 32 * j;
            const float* xm = xb + (size_t)m * CIN;
            float d = 0.f;
            if constexpr (CIN % 4 == 0) {
                for (int i4 = 0; i4 < CIN / 4; ++i4) {
                    float4 a = *(const float4*)&ctr[r][4 * i4];
                    float4 bv = *(const float4*)&xm[4 * i4];
                    d += a.x * bv.x + a.y * bv.y + a.z * bv.z + a.w * bv.w;
                }
            } else {
                for (int i = 0; i < CIN; ++i) d += ctr[r][i] * xm[i];
            }
            dist[r][m] = 2.f * d - sqr - sqb[m];
        }
    }
    __syncthreads();

    // top-20 selection: wave w handles rows w and w+4
    int wave = t >> 6, lane = t & 63;
    for (int rr = wave; rr < ROWS; rr += 4) {
        float v[16];
#pragma unroll
        for (int j = 0; j < 16; ++j) v[j] = dist[rr][lane + 64 * j];  // conflict-free
        int* op = idx + (size_t)(bb * N_ + r0 + rr) * K_;
        for (int it = 0; it < K_; ++it) {
            float bv = v[0];
            int bj = 0;
#pragma unroll
            for (int j = 1; j < 16; ++j) {
                if (v[j] > bv) { bv = v[j]; bj = j; }
            }
            int bidx = lane + 64 * bj;
#pragma unroll
            for (int off = 32; off > 0; off >>= 1) {
                float ov = __shfl_xor(bv, off);
                int oi = __shfl_xor(bidx, off);
                if (ov > bv || (ov == bv && oi < bidx)) { bv = ov; bidx = oi; }
            }
            if (lane == 0) op[it] = bidx;
            if ((bidx & 63) == lane) {
                int wj = bidx >> 6;
#pragma unroll
                for (int j = 0; j < 16; ++j)
                    if (j == wj) v[j] = -INFINITY;
            }
        }
    }
}

// ---------------------------------------------------------------- weight prep
// wdT[i][o] = a_o * W[o][i]   (first CIN cols of W)
// wcdT[i][o] = a_o * (W[o][CIN+i] - W[o][i])
// bias2[o] = b_o - m_o * a_o
template <int CIN, int COUT>
__global__ __launch_bounds__(256) void prep_kernel(const float* __restrict__ w,
                                                   const float* __restrict__ g,
                                                   const float* __restrict__ bb,
                                                   const float* __restrict__ m,
                                                   const float* __restrict__ v,
                                                   float* __restrict__ wdT,
                                                   float* __restrict__ wcdT,
                                                   float* __restrict__ bias2) {
    int e = blockIdx.x * 256 + threadIdx.x;
    if (e >= CIN * COUT) return;
    int o = e % COUT;
    int i = e / COUT;
    float a = g[o] / sqrtf(v[o] + EPS_);
    float wd = w[o * 2 * CIN + i];
    wdT[e] = a * wd;
    wcdT[e] = a * (w[o * 2 * CIN + CIN + i] - wd);
    if (i == 0) bias2[o] = bb[o] - m[o] * a;
}

// ---------------------------------------------------------------- edge conv
// One block per point. Each thread handles OO output channels, 20 k-accs each.
template <int CIN, int COUT, int OO>
__global__ __launch_bounds__(COUT / OO) void conv_kernel(
    const float* __restrict__ x, const int* __restrict__ idx,
    const float* __restrict__ wdT, const float* __restrict__ wcdT,
    const float* __restrict__ bias2, float* __restrict__ out) {
    constexpr int TH = COUT / OO;
    __shared__ __align__(16) float nb[K_][CIN];
    __shared__ float ctr[CIN];
    __shared__ int nidx[K_];
    int p = blockIdx.x;
    int bb = p >> 10;
    int t = threadIdx.x;
    if (t < K_) nidx[t] = idx[(size_t)p * K_ + t];
    for (int c = t; c < CIN; c += TH) ctr[c] = x[(size_t)p * CIN + c];
    __syncthreads();
    for (int e = t; e < K_ * CIN; e += TH) {
        int k = e / CIN, c = e % CIN;
        nb[k][c] = x[(size_t)(bb * N_ + nidx[k]) * CIN + c];
    }
    __syncthreads();

    float tacc[OO];
    float acc[OO][K_];
#pragma unroll
    for (int oo = 0; oo < OO; ++oo) {
        tacc[oo] = bias2[t + oo * TH];
#pragma unroll
        for (int k = 0; k < K_; ++k) acc[oo][k] = 0.f;
    }
    // ctr term: (Wc - Wd) . ctr
    for (int i = 0; i < CIN; ++i) {
        float cv = ctr[i];
#pragma unroll
        for (int oo = 0; oo < OO; ++oo) tacc[oo] += wcdT[i * COUT + t + oo * TH] * cv;
    }
    // neighbor term: Wd . nb_k
    if constexpr (CIN % 4 == 0) {
        for (int i4 = 0; i4 < CIN / 4; ++i4) {
            float4 w[OO];
#pragma unroll
            for (int oo = 0; oo < OO; ++oo) {
                int o = t + oo * TH;
                w[oo].x = wdT[(4 * i4 + 0) * COUT + o];
                w[oo].y = wdT[(4 * i4 + 1) * COUT + o];
                w[oo].z = wdT[(4 * i4 + 2) * COUT + o];
                w[oo].w = wdT[(4 * i4 + 3) * COUT + o];
            }
#pragma unroll
            for (int k = 0; k < K_; ++k) {
                float4 nv = *(const float4*)&nb[k][4 * i4];
#pragma unroll
                for (int oo = 0; oo < OO; ++oo)
                    acc[oo][k] += w[oo].x * nv.x + w[oo].y * nv.y + w[oo].z * nv.z +
                                  w[oo].w * nv.w;
            }
        }
    } else {
        for (int i = 0; i < CIN; ++i) {
            float w[OO];
#pragma unroll
            for (int oo = 0; oo < OO; ++oo) w[oo] = wdT[i * COUT + t + oo * TH];
#pragma unroll
            for (int k = 0; k < K_; ++k) {
                float nv = nb[k][i];
#pragma unroll
                for (int oo = 0; oo < OO; ++oo) acc[oo][k] += w[oo] * nv;
            }
        }
    }
    // lrelu(acc + tacc), max over k
#pragma unroll
    for (int oo = 0; oo < OO; ++oo) {
        float mx = -INFINITY;
#pragma unroll
        for (int k = 0; k < K_; ++k) {
            float val = acc[oo][k] + tacc[oo];
            val = (val >= 0.f) ? val : 0.2f * val;
            mx = fmaxf(mx, val);
        }
        out[(size_t)p * COUT + t + oo * TH] = mx;
    }
}

// ---------------------------------------------------------------- global max pool
template <int C>
__global__ __launch_bounds__(256) void pool_kernel(const float* __restrict__ h,
                                                   float* __restrict__ f, int off) {
    __shared__ float red[4][64];
    int bb = blockIdx.x / (C / 64);
    int c0 = (blockIdx.x % (C / 64)) * 64;
    int lane = threadIdx.x & 63, sl = threadIdx.x >> 6;
    int c = c0 + lane;
    const float* hb = h + (size_t)bb * N_ * C;
    float mx = -INFINITY;
    for (int n = sl * 256; n < sl * 256 + 256; ++n) mx = fmaxf(mx, hb[(size_t)n * C + c]);
    red[sl][lane] = mx;
    __syncthreads();
    if (sl == 0) {
        mx = fmaxf(fmaxf(red[0][lane], red[1][lane]), fmaxf(red[2][lane], red[3][lane]));
        f[bb * 384 + off + c] = mx;
    }
}

// ---------------------------------------------------------------- FC tail
__global__ __launch_bounds__(128) void fc_tail(
    const float* __restrict__ f, const float* __restrict__ f1w,
    const float* __restrict__ f1b, const float* __restrict__ n1g,
    const float* __restrict__ n1b, const float* __restrict__ n1m,
    const float* __restrict__ n1v, const float* __restrict__ f2w,
    const float* __restrict__ f2b, const float* __restrict__ n2g,
    const float* __restrict__ n2b, const float* __restrict__ n2m,
    const float* __restrict__ n2v, const float* __restrict__ f3w,
    const float* __restrict__ f3b, float* __restrict__ out) {
    __shared__ float fb[384];
    __shared__ float s1[128];
    __shared__ float s2[16];
    int bb = blockIdx.x, t = threadIdx.x;
    for (int j = t; j < 384; j += 128) fb[j] = f[bb * 384 + j];
    __syncthreads();
    float a = f1b[t];
    for (int j = 0; j < 384; ++j) a += f1w[t * 384 + j] * fb[j];
    a = (a - n1m[t]) * (n1g[t] / sqrtf(n1v[t] + EPS_)) + n1b[t];
    s1[t] = fmaxf(a, 0.f);
    __syncthreads();
    if (t < 16) {
        float a2 = f2b[t];
        for (int j = 0; j < 128; ++j) a2 += f2w[t * 128 + j] * s1[j];
        a2 = (a2 - n2m[t]) * (n2g[t] / sqrtf(n2v[t] + EPS_)) + n2b[t];
        s2[t] = fmaxf(a2, 0.f);
    }
    __syncthreads();
    if (t == 0) {
        float a3 = f3b[0];
        for (int j = 0; j < 16; ++j) a3 += f3w[j] * s2[j];
        out[bb] = a3;
    }
}

// ---------------------------------------------------------------- launch
extern "C" void kernel_launch(void* const* d_in, const int* in_sizes, int n_in,
                              void* d_out, int out_size, void* d_ws, size_t ws_size,
                              hipStream_t stream) {
    const float* x = (const float*)d_in[0];
    const float* cw[4] = {(const float*)d_in[1], (const float*)d_in[6],
                          (const float*)d_in[11], (const float*)d_in[16]};
    const float* cg[4] = {(const float*)d_in[2], (const float*)d_in[7],
                          (const float*)d_in[12], (const float*)d_in[17]};
    const float* cb[4] = {(const float*)d_in[3], (const float*)d_in[8],
                          (const float*)d_in[13], (const float*)d_in[18]};
    const float* cm[4] = {(const float*)d_in[4], (const float*)d_in[9],
                          (const float*)d_in[14], (const float*)d_in[19]};
    const float* cv[4] = {(const float*)d_in[5], (const float*)d_in[10],
                          (const float*)d_in[15], (const float*)d_in[20]};
    const float* f1w = (const float*)d_in[21];
    const float* f1b = (const float*)d_in[22];
    const float* n1g = (const float*)d_in[23];
    const float* n1b = (const float*)d_in[24];
    const float* n1m = (const float*)d_in[25];
    const float* n1v = (const float*)d_in[26];
    const float* f2w = (const float*)d_in[27];
    const float* f2b = (const float*)d_in[28];
    const float* n2g = (const float*)d_in[29];
    const float* n2b = (const float*)d_in[30];
    const float* n2m = (const float*)d_in[31];
    const float* n2v = (const float*)d_in[32];
    const float* f3w = (const float*)d_in[33];
    const float* f3b = (const float*)d_in[34];
    float* out = (float*)d_out;

    // workspace carve-up
    char* ws = (char*)d_ws;
    size_t off = 0;
    auto alloc = [&](size_t bytes) {
        void* p = ws + off;
        off += (bytes + 255) & ~(size_t)255;
        return p;
    };
    float* sq = (float*)alloc(B_ * N_ * 4);
    int* idx = (int*)alloc((size_t)B_ * N_ * K_ * 4);
    float* h1 = (float*)alloc((size_t)B_ * N_ * 64 * 4);
    float* h2 = (float*)alloc((size_t)B_ * N_ * 64 * 4);
    float* h3 = (float*)alloc((size_t)B_ * N_ * 128 * 4);
    float* h4 = (float*)alloc((size_t)B_ * N_ * 256 * 4);
    float* wd = (float*)alloc(128 * 256 * 4);
    float* wcd = (float*)alloc(128 * 256 * 4);
    float* b2 = (float*)alloc(256 * 4);
    float* f = (float*)alloc(B_ * 384 * 4);
    (void)ws_size;
    (void)in_sizes;
    (void)n_in;
    (void)out_size;

    const int KB = B_ * (N_ / 8);  // knn grid

    // ---- layer 1: 3 -> 64
    sq_kernel<<<(B_ * N_) / 256, 256, 0, stream>>>(x, sq, 3);
    knn_kernel<3><<<KB, 256, 0, stream>>>(x, sq, idx);
    prep_kernel<3, 64><<<(3 * 64 + 255) / 256, 256, 0, stream>>>(cw[0], cg[0], cb[0],
                                                                 cm[0], cv[0], wd, wcd, b2);
    conv_kernel<3, 64, 1><<<B_ * N_, 64, 0, stream>>>(x, idx, wd, wcd, b2, h1);

    // ---- layer 2: 64 -> 64
    sq_kernel<<<(B_ * N_) / 256, 256, 0, stream>>>(h1, sq, 64);
    knn_kernel<64><<<KB, 256, 0, stream>>>(h1, sq, idx);
    prep_kernel<64, 64><<<(64 * 64 + 255) / 256, 256, 0, stream>>>(cw[1], cg[1], cb[1],
                                                                   cm[1], cv[1], wd, wcd, b2);
    conv_kernel<64, 64, 1><<<B_ * N_, 64, 0, stream>>>(h1, idx, wd, wcd, b2, h2);

    // ---- layer 3: 64 -> 128
    sq_kernel<<<(B_ * N_) / 256, 256, 0, stream>>>(h2, sq, 64);
    knn_kernel<64><<<KB, 256, 0, stream>>>(h2, sq, idx);
    prep_kernel<64, 128><<<(64 * 128 + 255) / 256, 256, 0, stream>>>(cw[2], cg[2], cb[2],
                                                                     cm[2], cv[2], wd, wcd, b2);
    conv_kernel<64, 128, 1><<<B_ * N_, 128, 0, stream>>>(h2, idx, wd, wcd, b2, h3);

    // ---- layer 4: 128 -> 256
    sq_kernel<<<(B_ * N_) / 256, 256, 0, stream>>>(h3, sq, 128);
    knn_kernel<128><<<KB, 256, 0, stream>>>(h3, sq, idx);
    prep_kernel<128, 256><<<(128 * 256 + 255) / 256, 256, 0, stream>>>(cw[3], cg[3], cb[3],
                                                                       cm[3], cv[3], wd, wcd, b2);
    conv_kernel<128, 256, 2><<<B_ * N_, 128, 0, stream>>>(h3, idx, wd, wcd, b2, h4);

    // ---- pooling + FC tail
    pool_kernel<128><<<B_ * 2, 256, 0, stream>>>(h3, f, 0);
    pool_kernel<256><<<B_ * 4, 256, 0, stream>>>(h4, f, 128);
    fc_tail<<<B_, 128, 0, stream>>>(f, f1w, f1b, n1g, n1b, n1m, n1v, f2w, f2b, n2g, n2b,
                                    n2m, n2v, f3w, f3b, out);
}

// Round 2
// 975.730 us; speedup vs baseline: 1.8858x; 1.8858x over previous
//
#include <hip/hip_runtime.h>
#include <math.h>

constexpr int B_ = 8;
constexpr int N_ = 1024;
constexpr int K_ = 20;
constexpr float EPS_ = 1e-5f;

// ---------------------------------------------------------------- layer-1 transpose + sq
__global__ __launch_bounds__(256) void xpose0_kernel(const float* __restrict__ x,
                                                     float* __restrict__ xT,
                                                     float* __restrict__ sq) {
    int t = blockIdx.x * 256 + threadIdx.x;   // global point id
    if (t >= B_ * N_) return;
    int b = t >> 10, n = t & 1023;
    float a = x[3 * t], c = x[3 * t + 1], d = x[3 * t + 2];
    xT[((size_t)b * 3 + 0) * N_ + n] = a;
    xT[((size_t)b * 3 + 1) * N_ + n] = c;
    xT[((size_t)b * 3 + 2) * N_ + n] = d;
    sq[t] = a * a + c * c + d * d;
}

// ---------------------------------------------------------------- sq kernel (templated C)
template <int C>
__global__ __launch_bounds__(256) void sqk_kernel(const float* __restrict__ h,
                                                  float* __restrict__ sq) {
    int p = blockIdx.x * 256 + threadIdx.x;
    if (p >= B_ * N_) return;
    const float4* r = (const float4*)(h + (size_t)p * C);
    float s = 0.f;
#pragma unroll
    for (int i = 0; i < C / 4; ++i) {
        float4 v = r[i];
        s += v.x * v.x + v.y * v.y + v.z * v.z + v.w * v.w;
    }
    sq[p] = s;
}

// ---------------------------------------------------------------- tiled transpose (N,C)->(C,N)
template <int C>
__global__ __launch_bounds__(256) void tr_kernel(const float* __restrict__ h,
                                                 float* __restrict__ hT) {
    __shared__ float tile[64][65];
    int n0 = blockIdx.x * 64, c0 = blockIdx.y * 64, b = blockIdx.z;
    const float* hb = h + (size_t)b * N_ * C;
    float* hTb = hT + (size_t)b * C * N_;
    int j = threadIdx.x & 63, i4 = threadIdx.x >> 6;
#pragma unroll
    for (int ii = 0; ii < 16; ++ii)
        tile[i4 * 16 + ii][j] = hb[(size_t)(n0 + i4 * 16 + ii) * C + c0 + j];
    __syncthreads();
#pragma unroll
    for (int ii = 0; ii < 16; ++ii)
        hTb[(size_t)(c0 + i4 * 16 + ii) * N_ + n0 + j] = tile[j][i4 * 16 + ii];
}

// ---------------------------------------------------------------- knn kernel (fused dist+topk)
__device__ __forceinline__ unsigned int fkey(float f) {
    unsigned int u = __float_as_uint(f);
    return (u & 0x80000000u) ? ~u : (u | 0x80000000u);
}

template <int CIN>
__global__ __launch_bounds__(256) void knn_kernel(const float* __restrict__ xT,
                                                  const float* __restrict__ xrow,
                                                  const float* __restrict__ sq,
                                                  int* __restrict__ idx) {
    constexpr int ROWS = 8;
    __shared__ float ctr[ROWS][CIN];
    __shared__ float sqr8[ROWS];
    int t = threadIdx.x;
    int bb = blockIdx.x / (N_ / ROWS);
    int r0 = (blockIdx.x % (N_ / ROWS)) * ROWS;
    const float* xtb = xT + (size_t)bb * CIN * N_;

    for (int e = t; e < ROWS * CIN; e += 256)
        ((float*)ctr)[e] = xrow[(size_t)(bb * N_ + r0) * CIN + e];
    if (t < ROWS) sqr8[t] = sq[bb * N_ + r0 + t];
    __syncthreads();

    int wave = t >> 6, lane = t & 63;
    int row0 = 2 * wave, row1 = 2 * wave + 1;
    int c0 = lane * 16;

    float acc0[16], acc1[16];
#pragma unroll
    for (int s = 0; s < 16; ++s) { acc0[s] = 0.f; acc1[s] = 0.f; }

#pragma unroll 4
    for (int ci = 0; ci < CIN; ++ci) {
        const float4* xr = (const float4*)(xtb + (size_t)ci * N_ + c0);
        float4 a = xr[0], b = xr[1], c = xr[2], d = xr[3];
        float col[16] = {a.x, a.y, a.z, a.w, b.x, b.y, b.z, b.w,
                         c.x, c.y, c.z, c.w, d.x, d.y, d.z, d.w};
        float p0 = ctr[row0][ci], p1 = ctr[row1][ci];
#pragma unroll
        for (int s = 0; s < 16; ++s) {
            acc0[s] = fmaf(p0, col[s], acc0[s]);
            acc1[s] = fmaf(p1, col[s], acc1[s]);
        }
    }

    // per-lane column sq values
    float sqc[16];
    {
        const float4* sr = (const float4*)(sq + bb * N_ + c0);
        float4 a = sr[0], b = sr[1], c = sr[2], d = sr[3];
        sqc[0] = a.x; sqc[1] = a.y; sqc[2] = a.z; sqc[3] = a.w;
        sqc[4] = b.x; sqc[5] = b.y; sqc[6] = b.z; sqc[7] = b.w;
        sqc[8] = c.x; sqc[9] = c.y; sqc[10] = c.z; sqc[11] = c.w;
        sqc[12] = d.x; sqc[13] = d.y; sqc[14] = d.z; sqc[15] = d.w;
    }

    // ---- selection for the wave's two rows
#pragma unroll
    for (int rr = 0; rr < 2; ++rr) {
        float* acc = rr ? acc1 : acc0;
        float sqr = sqr8[rr ? row1 : row0];
        int* op = idx + (size_t)(bb * N_ + r0 + (rr ? row1 : row0)) * K_;
        unsigned long long v[16];
#pragma unroll
        for (int s = 0; s < 16; ++s) {
            float dd = 2.f * acc[s] - sqr - sqc[s];
            v[s] = ((unsigned long long)fkey(dd) << 32) | (unsigned int)(~(c0 + s));
        }
        for (int it = 0; it < K_; ++it) {
            // local max: tree (depth 4)
            unsigned long long t0[8];
#pragma unroll
            for (int s = 0; s < 8; ++s) t0[s] = v[2 * s] > v[2 * s + 1] ? v[2 * s] : v[2 * s + 1];
#pragma unroll
            for (int s = 0; s < 4; ++s) t0[s] = t0[2 * s] > t0[2 * s + 1] ? t0[2 * s] : t0[2 * s + 1];
            t0[0] = t0[0] > t0[1] ? t0[0] : t0[1];
            t0[2] = t0[2] > t0[3] ? t0[2] : t0[3];
            unsigned long long m = t0[0] > t0[2] ? t0[0] : t0[2];
            // wave max: 6-level butterfly on u64
#pragma unroll
            for (int off = 32; off; off >>= 1) {
                unsigned long long o = __shfl_xor(m, off);
                m = o > m ? o : m;
            }
            if (lane == 0) op[it] = (int)(~(unsigned int)m);
            // remove winner (keys unique: only owner matches)
#pragma unroll
            for (int s = 0; s < 16; ++s) v[s] = (v[s] == m) ? 0ull : v[s];
        }
    }
}

// ---------------------------------------------------------------- weight prep
template <int CIN, int COUT>
__global__ __launch_bounds__(256) void prep_kernel(const float* __restrict__ w,
                                                   const float* __restrict__ g,
                                                   const float* __restrict__ bb,
                                                   const float* __restrict__ m,
                                                   const float* __restrict__ v,
                                                   float* __restrict__ wdT,
                                                   float* __restrict__ wcdT,
                                                   float* __restrict__ bias2) {
    int e = blockIdx.x * 256 + threadIdx.x;
    if (e >= CIN * COUT) return;
    int o = e % COUT;
    int i = e / COUT;
    float a = g[o] / sqrtf(v[o] + EPS_);
    float wd = w[o * 2 * CIN + i];
    wdT[e] = a * wd;
    wcdT[e] = a * (w[o * 2 * CIN + CIN + i] - wd);
    if (i == 0) bias2[o] = bb[o] - m[o] * a;
}

// ---------------------------------------------------------------- edge conv
template <int CIN, int COUT, int OO>
__global__ __launch_bounds__(COUT / OO) void conv_kernel(
    const float* __restrict__ x, const int* __restrict__ idx,
    const float* __restrict__ wdT, const float* __restrict__ wcdT,
    const float* __restrict__ bias2, float* __restrict__ out) {
    constexpr int TH = COUT / OO;
    __shared__ __align__(16) float nb[K_][CIN];
    __shared__ float ctr[CIN];
    __shared__ int nidx[K_];
    int p = blockIdx.x;
    int bb = p >> 10;
    int t = threadIdx.x;
    if (t < K_) nidx[t] = idx[(size_t)p * K_ + t];
    for (int c = t; c < CIN; c += TH) ctr[c] = x[(size_t)p * CIN + c];
    __syncthreads();
    for (int e = t; e < K_ * CIN; e += TH) {
        int k = e / CIN, c = e % CIN;
        nb[k][c] = x[(size_t)(bb * N_ + nidx[k]) * CIN + c];
    }
    __syncthreads();

    float tacc[OO];
    float acc[OO][K_];
#pragma unroll
    for (int oo = 0; oo < OO; ++oo) {
        tacc[oo] = bias2[t + oo * TH];
#pragma unroll
        for (int k = 0; k < K_; ++k) acc[oo][k] = 0.f;
    }
    for (int i = 0; i < CIN; ++i) {
        float cv = ctr[i];
#pragma unroll
        for (int oo = 0; oo < OO; ++oo) tacc[oo] += wcdT[i * COUT + t + oo * TH] * cv;
    }
    if constexpr (CIN % 4 == 0) {
        for (int i4 = 0; i4 < CIN / 4; ++i4) {
            float4 w[OO];
#pragma unroll
            for (int oo = 0; oo < OO; ++oo) {
                int o = t + oo * TH;
                w[oo].x = wdT[(4 * i4 + 0) * COUT + o];
                w[oo].y = wdT[(4 * i4 + 1) * COUT + o];
                w[oo].z = wdT[(4 * i4 + 2) * COUT + o];
                w[oo].w = wdT[(4 * i4 + 3) * COUT + o];
            }
#pragma unroll
            for (int k = 0; k < K_; ++k) {
                float4 nv = *(const float4*)&nb[k][4 * i4];
#pragma unroll
                for (int oo = 0; oo < OO; ++oo)
                    acc[oo][k] += w[oo].x * nv.x + w[oo].y * nv.y + w[oo].z * nv.z +
                                  w[oo].w * nv.w;
            }
        }
    } else {
        for (int i = 0; i < CIN; ++i) {
            float w[OO];
#pragma unroll
            for (int oo = 0; oo < OO; ++oo) w[oo] = wdT[i * COUT + t + oo * TH];
#pragma unroll
            for (int k = 0; k < K_; ++k) {
                float nv = nb[k][i];
#pragma unroll
                for (int oo = 0; oo < OO; ++oo) acc[oo][k] += w[oo] * nv;
            }
        }
    }
#pragma unroll
    for (int oo = 0; oo < OO; ++oo) {
        float mx = -INFINITY;
#pragma unroll
        for (int k = 0; k < K_; ++k) {
            float val = acc[oo][k] + tacc[oo];
            val = (val >= 0.f) ? val : 0.2f * val;
            mx = fmaxf(mx, val);
        }
        out[(size_t)p * COUT + t + oo * TH] = mx;
    }
}

// ---------------------------------------------------------------- global max pool
template <int C>
__global__ __launch_bounds__(256) void pool_kernel(const float* __restrict__ h,
                                                   float* __restrict__ f, int off) {
    __shared__ float red[4][64];
    int bb = blockIdx.x / (C / 64);
    int c0 = (blockIdx.x % (C / 64)) * 64;
    int lane = threadIdx.x & 63, sl = threadIdx.x >> 6;
    int c = c0 + lane;
    const float* hb = h + (size_t)bb * N_ * C;
    float mx = -INFINITY;
    for (int n = sl * 256; n < sl * 256 + 256; ++n) mx = fmaxf(mx, hb[(size_t)n * C + c]);
    red[sl][lane] = mx;
    __syncthreads();
    if (sl == 0) {
        mx = fmaxf(fmaxf(red[0][lane], red[1][lane]), fmaxf(red[2][lane], red[3][lane]));
        f[bb * 384 + off + c] = mx;
    }
}

// ---------------------------------------------------------------- FC tail
__global__ __launch_bounds__(128) void fc_tail(
    const float* __restrict__ f, const float* __restrict__ f1w,
    const float* __restrict__ f1b, const float* __restrict__ n1g,
    const float* __restrict__ n1b, const float* __restrict__ n1m,
    const float* __restrict__ n1v, const float* __restrict__ f2w,
    const float* __restrict__ f2b, const float* __restrict__ n2g,
    const float* __restrict__ n2b, const float* __restrict__ n2m,
    const float* __restrict__ n2v, const float* __restrict__ f3w,
    const float* __restrict__ f3b, float* __restrict__ out) {
    __shared__ float fb[384];
    __shared__ float s1[128];
    __shared__ float s2[16];
    int bb = blockIdx.x, t = threadIdx.x;
    for (int j = t; j < 384; j += 128) fb[j] = f[bb * 384 + j];
    __syncthreads();
    float a = f1b[t];
    for (int j = 0; j < 384; ++j) a += f1w[t * 384 + j] * fb[j];
    a = (a - n1m[t]) * (n1g[t] / sqrtf(n1v[t] + EPS_)) + n1b[t];
    s1[t] = fmaxf(a, 0.f);
    __syncthreads();
    if (t < 16) {
        float a2 = f2b[t];
        for (int j = 0; j < 128; ++j) a2 += f2w[t * 128 + j] * s1[j];
        a2 = (a2 - n2m[t]) * (n2g[t] / sqrtf(n2v[t] + EPS_)) + n2b[t];
        s2[t] = fmaxf(a2, 0.f);
    }
    __syncthreads();
    if (t == 0) {
        float a3 = f3b[0];
        for (int j = 0; j < 16; ++j) a3 += f3w[j] * s2[j];
        out[bb] = a3;
    }
}

// ---------------------------------------------------------------- launch
extern "C" void kernel_launch(void* const* d_in, const int* in_sizes, int n_in,
                              void* d_out, int out_size, void* d_ws, size_t ws_size,
                              hipStream_t stream) {
    const float* x = (const float*)d_in[0];
    const float* cw[4] = {(const float*)d_in[1], (const float*)d_in[6],
                          (const float*)d_in[11], (const float*)d_in[16]};
    const float* cg[4] = {(const float*)d_in[2], (const float*)d_in[7],
                          (const float*)d_in[12], (const float*)d_in[17]};
    const float* cb[4] = {(const float*)d_in[3], (const float*)d_in[8],
                          (const float*)d_in[13], (const float*)d_in[18]};
    const float* cm[4] = {(const float*)d_in[4], (const float*)d_in[9],
                          (const float*)d_in[14], (const float*)d_in[19]};
    const float* cv[4] = {(const float*)d_in[5], (const float*)d_in[10],
                          (const float*)d_in[15], (const float*)d_in[20]};
    const float* f1w = (const float*)d_in[21];
    const float* f1b = (const float*)d_in[22];
    const float* n1g = (const float*)d_in[23];
    const float* n1b = (const float*)d_in[24];
    const float* n1m = (const float*)d_in[25];
    const float* n1v = (const float*)d_in[26];
    const float* f2w = (const float*)d_in[27];
    const float* f2b = (const float*)d_in[28];
    const float* n2g = (const float*)d_in[29];
    const float* n2b = (const float*)d_in[30];
    const float* n2m = (const float*)d_in[31];
    const float* n2v = (const float*)d_in[32];
    const float* f3w = (const float*)d_in[33];
    const float* f3b = (const float*)d_in[34];
    float* out = (float*)d_out;

    char* ws = (char*)d_ws;
    size_t off = 0;
    auto alloc = [&](size_t bytes) {
        void* p = ws + off;
        off += (bytes + 255) & ~(size_t)255;
        return p;
    };
    float* sq = (float*)alloc(B_ * N_ * 4);
    int* idx = (int*)alloc((size_t)B_ * N_ * K_ * 4);
    float* h1 = (float*)alloc((size_t)B_ * N_ * 64 * 4);
    float* h2 = (float*)alloc((size_t)B_ * N_ * 64 * 4);
    float* h3 = (float*)alloc((size_t)B_ * N_ * 128 * 4);
    float* h4 = (float*)alloc((size_t)B_ * N_ * 256 * 4);
    float* wd = (float*)alloc(128 * 256 * 4);
    float* wcd = (float*)alloc(128 * 256 * 4);
    float* b2 = (float*)alloc(256 * 4);
    float* f = (float*)alloc(B_ * 384 * 4);
    float* xT = (float*)alloc((size_t)B_ * 3 * N_ * 4);
    float* hT = (float*)alloc((size_t)B_ * 128 * N_ * 4);  // max C=128 transposed
    (void)ws_size; (void)in_sizes; (void)n_in; (void)out_size;

    const int KB = B_ * (N_ / 8);  // knn grid (8 rows per block)

    // ---- layer 1: 3 -> 64
    xpose0_kernel<<<(B_ * N_) / 256, 256, 0, stream>>>(x, xT, sq);
    knn_kernel<3><<<KB, 256, 0, stream>>>(xT, x, sq, idx);
    prep_kernel<3, 64><<<1, 256, 0, stream>>>(cw[0], cg[0], cb[0], cm[0], cv[0], wd, wcd, b2);
    conv_kernel<3, 64, 1><<<B_ * N_, 64, 0, stream>>>(x, idx, wd, wcd, b2, h1);

    // ---- layer 2: 64 -> 64
    sqk_kernel<64><<<(B_ * N_) / 256, 256, 0, stream>>>(h1, sq);
    tr_kernel<64><<<dim3(N_ / 64, 1, B_), 256, 0, stream>>>(h1, hT);
    knn_kernel<64><<<KB, 256, 0, stream>>>(hT, h1, sq, idx);
    prep_kernel<64, 64><<<16, 256, 0, stream>>>(cw[1], cg[1], cb[1], cm[1], cv[1], wd, wcd, b2);
    conv_kernel<64, 64, 1><<<B_ * N_, 64, 0, stream>>>(h1, idx, wd, wcd, b2, h2);

    // ---- layer 3: 64 -> 128
    sqk_kernel<64><<<(B_ * N_) / 256, 256, 0, stream>>>(h2, sq);
    tr_kernel<64><<<dim3(N_ / 64, 1, B_), 256, 0, stream>>>(h2, hT);
    knn_kernel<64><<<KB, 256, 0, stream>>>(hT, h2, sq, idx);
    prep_kernel<64, 128><<<32, 256, 0, stream>>>(cw[2], cg[2], cb[2], cm[2], cv[2], wd, wcd, b2);
    conv_kernel<64, 128, 1><<<B_ * N_, 128, 0, stream>>>(h2, idx, wd, wcd, b2, h3);

    // ---- layer 4: 128 -> 256
    sqk_kernel<128><<<(B_ * N_) / 256, 256, 0, stream>>>(h3, sq);
    tr_kernel<128><<<dim3(N_ / 64, 2, B_), 256, 0, stream>>>(h3, hT);
    knn_kernel<128><<<KB, 256, 0, stream>>>(hT, h3, sq, idx);
    prep_kernel<128, 256><<<128, 256, 0, stream>>>(cw[3], cg[3], cb[3], cm[3], cv[3], wd, wcd, b2);
    conv_kernel<128, 256, 2><<<B_ * N_, 128, 0, stream>>>(h3, idx, wd, wcd, b2, h4);

    // ---- pooling + FC tail
    pool_kernel<128><<<B_ * 2, 256, 0, stream>>>(h3, f, 0);
    pool_kernel<256><<<B_ * 4, 256, 0, stream>>>(h4, f, 128);
    fc_tail<<<B_, 128, 0, stream>>>(f, f1w, f1b, n1g, n1b, n1m, n1v, f2w, f2b, n2g, n2b,
                                    n2m, n2v, f3w, f3b, out);
}

// Round 3
// 733.143 us; speedup vs baseline: 2.5098x; 1.3309x over previous
//
#include <hip/hip_runtime.h>
#include <math.h>

constexpr int B_ = 8;
constexpr int N_ = 1024;
constexpr int K_ = 20;
constexpr float EPS_ = 1e-5f;

typedef __attribute__((ext_vector_type(8))) short short8;
typedef __attribute__((ext_vector_type(4))) float f32x4;

// hi/lo bf16 split (RNE both halves)
__device__ __forceinline__ void bf16split(float x, unsigned short& h, unsigned short& l) {
    unsigned u = __float_as_uint(x);
    unsigned rh = (u + 0x7FFFu + ((u >> 16) & 1u)) >> 16;
    h = (unsigned short)rh;
    float lof = x - __uint_as_float(rh << 16);
    unsigned ul = __float_as_uint(lof);
    l = (unsigned short)((ul + 0x7FFFu + ((ul >> 16) & 1u)) >> 16);
}

// ---------------------------------------------------------------- layer-1 transpose + sq
__global__ __launch_bounds__(256) void xpose0_kernel(const float* __restrict__ x,
                                                     float* __restrict__ xT,
                                                     float* __restrict__ sq) {
    int t = blockIdx.x * 256 + threadIdx.x;
    if (t >= B_ * N_) return;
    int b = t >> 10, n = t & 1023;
    float a = x[3 * t], c = x[3 * t + 1], d = x[3 * t + 2];
    xT[((size_t)b * 3 + 0) * N_ + n] = a;
    xT[((size_t)b * 3 + 1) * N_ + n] = c;
    xT[((size_t)b * 3 + 2) * N_ + n] = d;
    sq[t] = a * a + c * c + d * d;
}

// ---------------------------------------------------------------- sq kernel
template <int C>
__global__ __launch_bounds__(256) void sqk_kernel(const float* __restrict__ h,
                                                  float* __restrict__ sq) {
    int p = blockIdx.x * 256 + threadIdx.x;
    if (p >= B_ * N_) return;
    const float4* r = (const float4*)(h + (size_t)p * C);
    float s = 0.f;
#pragma unroll
    for (int i = 0; i < C / 4; ++i) {
        float4 v = r[i];
        s += v.x * v.x + v.y * v.y + v.z * v.z + v.w * v.w;
    }
    sq[p] = s;
}

// ---------------------------------------------------------------- tiled transpose
template <int C>
__global__ __launch_bounds__(256) void tr_kernel(const float* __restrict__ h,
                                                 float* __restrict__ hT) {
    __shared__ float tile[64][65];
    int n0 = blockIdx.x * 64, c0 = blockIdx.y * 64, b = blockIdx.z;
    const float* hb = h + (size_t)b * N_ * C;
    float* hTb = hT + (size_t)b * C * N_;
    int j = threadIdx.x & 63, i4 = threadIdx.x >> 6;
#pragma unroll
    for (int ii = 0; ii < 16; ++ii)
        tile[i4 * 16 + ii][j] = hb[(size_t)(n0 + i4 * 16 + ii) * C + c0 + j];
    __syncthreads();
#pragma unroll
    for (int ii = 0; ii < 16; ++ii)
        hTb[(size_t)(c0 + i4 * 16 + ii) * N_ + n0 + j] = tile[j][i4 * 16 + ii];
}

// ---------------------------------------------------------------- knn kernel
__device__ __forceinline__ unsigned int fkey(float f) {
    unsigned int u = __float_as_uint(f);
    return (u & 0x80000000u) ? ~u : (u | 0x80000000u);
}

template <int CIN>
__global__ __launch_bounds__(256) void knn_kernel(const float* __restrict__ xT,
                                                  const float* __restrict__ xrow,
                                                  const float* __restrict__ sq,
                                                  int* __restrict__ idx) {
    constexpr int ROWS = 8;
    __shared__ float ctr[ROWS][CIN];
    __shared__ float sqr8[ROWS];
    int t = threadIdx.x;
    int bb = blockIdx.x / (N_ / ROWS);
    int r0 = (blockIdx.x % (N_ / ROWS)) * ROWS;
    const float* xtb = xT + (size_t)bb * CIN * N_;

    for (int e = t; e < ROWS * CIN; e += 256)
        ((float*)ctr)[e] = xrow[(size_t)(bb * N_ + r0) * CIN + e];
    if (t < ROWS) sqr8[t] = sq[bb * N_ + r0 + t];
    __syncthreads();

    int wave = t >> 6, lane = t & 63;
    int row0 = 2 * wave, row1 = 2 * wave + 1;
    int c0 = lane * 16;

    float acc0[16], acc1[16];
#pragma unroll
    for (int s = 0; s < 16; ++s) { acc0[s] = 0.f; acc1[s] = 0.f; }

#pragma unroll 4
    for (int ci = 0; ci < CIN; ++ci) {
        const float4* xr = (const float4*)(xtb + (size_t)ci * N_ + c0);
        float4 a = xr[0], b = xr[1], c = xr[2], d = xr[3];
        float col[16] = {a.x, a.y, a.z, a.w, b.x, b.y, b.z, b.w,
                         c.x, c.y, c.z, c.w, d.x, d.y, d.z, d.w};
        float p0 = ctr[row0][ci], p1 = ctr[row1][ci];
#pragma unroll
        for (int s = 0; s < 16; ++s) {
            acc0[s] = fmaf(p0, col[s], acc0[s]);
            acc1[s] = fmaf(p1, col[s], acc1[s]);
        }
    }

    float sqc[16];
    {
        const float4* sr = (const float4*)(sq + bb * N_ + c0);
        float4 a = sr[0], b = sr[1], c = sr[2], d = sr[3];
        sqc[0] = a.x; sqc[1] = a.y; sqc[2] = a.z; sqc[3] = a.w;
        sqc[4] = b.x; sqc[5] = b.y; sqc[6] = b.z; sqc[7] = b.w;
        sqc[8] = c.x; sqc[9] = c.y; sqc[10] = c.z; sqc[11] = c.w;
        sqc[12] = d.x; sqc[13] = d.y; sqc[14] = d.z; sqc[15] = d.w;
    }

#pragma unroll
    for (int rr = 0; rr < 2; ++rr) {
        float* acc = rr ? acc1 : acc0;
        float sqr = sqr8[rr ? row1 : row0];
        int* op = idx + (size_t)(bb * N_ + r0 + (rr ? row1 : row0)) * K_;
        unsigned long long v[16];
#pragma unroll
        for (int s = 0; s < 16; ++s) {
            float dd = 2.f * acc[s] - sqr - sqc[s];
            v[s] = ((unsigned long long)fkey(dd) << 32) | (unsigned int)(~(c0 + s));
        }
        for (int it = 0; it < K_; ++it) {
            unsigned long long t0[8];
#pragma unroll
            for (int s = 0; s < 8; ++s) t0[s] = v[2 * s] > v[2 * s + 1] ? v[2 * s] : v[2 * s + 1];
#pragma unroll
            for (int s = 0; s < 4; ++s) t0[s] = t0[2 * s] > t0[2 * s + 1] ? t0[2 * s] : t0[2 * s + 1];
            t0[0] = t0[0] > t0[1] ? t0[0] : t0[1];
            t0[2] = t0[2] > t0[3] ? t0[2] : t0[3];
            unsigned long long m = t0[0] > t0[2] ? t0[0] : t0[2];
#pragma unroll
            for (int off = 32; off; off >>= 1) {
                unsigned long long o = __shfl_xor(m, off);
                m = o > m ? o : m;
            }
            if (lane == 0) op[it] = (int)(~(unsigned int)m);
#pragma unroll
            for (int s = 0; s < 16; ++s) v[s] = (v[s] == m) ? 0ull : v[s];
        }
    }
}

// ---------------------------------------------------------------- fp32 weight prep (L1)
template <int CIN, int COUT>
__global__ __launch_bounds__(256) void prep_kernel(const float* __restrict__ w,
                                                   const float* __restrict__ g,
                                                   const float* __restrict__ bb,
                                                   const float* __restrict__ m,
                                                   const float* __restrict__ v,
                                                   float* __restrict__ wdT,
                                                   float* __restrict__ wcdT,
                                                   float* __restrict__ bias2) {
    int e = blockIdx.x * 256 + threadIdx.x;
    if (e >= CIN * COUT) return;
    int o = e % COUT;
    int i = e / COUT;
    float a = g[o] / sqrtf(v[o] + EPS_);
    float wd = w[o * 2 * CIN + i];
    wdT[e] = a * wd;
    wcdT[e] = a * (w[o * 2 * CIN + CIN + i] - wd);
    if (i == 0) bias2[o] = bb[o] - m[o] * a;
}

// ---------------------------------------------------------------- MFMA weight prep
// Writes Wd (BN-folded) hi/lo in B-fragment order: B[k=quad*8+j][n=nt*16+nl],
// lane = quad*16+nl, flat = ((kc*NT+nt)*64+lane)*8+j. Also wcdT + bias2.
template <int CIN, int COUT>
__global__ __launch_bounds__(256) void prep_mfma(const float* __restrict__ w,
                                                 const float* __restrict__ g,
                                                 const float* __restrict__ bb,
                                                 const float* __restrict__ m,
                                                 const float* __restrict__ v,
                                                 unsigned short* __restrict__ Wh,
                                                 unsigned short* __restrict__ Wl,
                                                 float* __restrict__ wcdT,
                                                 float* __restrict__ bias2) {
    int e = blockIdx.x * 256 + threadIdx.x;
    if (e >= CIN * COUT) return;
    int n = e % COUT, k = e / COUT;
    float a = g[n] / sqrtf(v[n] + EPS_);
    float wdv = a * w[n * 2 * CIN + k];
    unsigned short h, l;
    bf16split(wdv, h, l);
    int kc = k >> 5, ko = k & 31, quad = ko >> 3, j = ko & 7;
    int nt = n >> 4, nl = n & 15;
    constexpr int NT = COUT / 16;
    size_t pos = ((size_t)(kc * NT + nt) * 64 + quad * 16 + nl) * 8 + j;
    Wh[pos] = h;
    Wl[pos] = l;
    wcdT[k * COUT + n] = a * (w[n * 2 * CIN + CIN + k] - w[n * 2 * CIN + k]);
    if (k == 0) bias2[n] = bb[n] - m[n] * a;
}

// ---------------------------------------------------------------- ctr-term (fp32)
// ct[p][o] = bias2[o] + sum_i wcdT[i][o]*x[p][i];  PP points per block.
template <int CIN, int COUT, int PP>
__global__ __launch_bounds__(COUT) void cterm_kernel(const float* __restrict__ x,
                                                     const float* __restrict__ wcdT,
                                                     const float* __restrict__ bias2,
                                                     float* __restrict__ ct) {
    __shared__ float ctr[PP][CIN];
    int p0 = blockIdx.x * PP;
    int t = threadIdx.x;
    for (int e = t; e < PP * CIN; e += COUT)
        ctr[e / CIN][e % CIN] = x[(size_t)p0 * CIN + e];
    __syncthreads();
    float acc[PP];
#pragma unroll
    for (int pp = 0; pp < PP; ++pp) acc[pp] = bias2[t];
    for (int i = 0; i < CIN; ++i) {
        float w = wcdT[i * COUT + t];
#pragma unroll
        for (int pp = 0; pp < PP; ++pp) acc[pp] = fmaf(w, ctr[pp][i], acc[pp]);
    }
#pragma unroll
    for (int pp = 0; pp < PP; ++pp) ct[(size_t)(p0 + pp) * COUT + t] = acc[pp];
}

// ---------------------------------------------------------------- MFMA edge conv
// Block: P points (P*20 rows), 256 threads (4 waves), wave w covers cols
// [64w, 64w+64). Split-bf16: acc += Ah*Bh + Ah*Bl + Al*Bh.
template <int CIN, int COUT, int P>
__global__ __launch_bounds__(256) void convm_kernel(const float* __restrict__ x,
                                                    const int* __restrict__ idx,
                                                    const unsigned short* __restrict__ Wh,
                                                    const unsigned short* __restrict__ Wl,
                                                    const float* __restrict__ cterm,
                                                    float* __restrict__ out) {
    constexpr int ROWS = P * K_;
    constexpr int MT = ROWS / 16;
    constexpr int NT = COUT / 16;
    constexpr int NTW = NT / 4;
    constexpr int KC = CIN / 32;
    constexpr int STR = CIN + 8;  // shorts; keeps b128 reads ~2-way at most
    __shared__ unsigned short Ahi[ROWS * STR];
    __shared__ unsigned short Alo[ROWS * STR];
    __shared__ int nidx[ROWS];

    int t = threadIdx.x;
    int bb = blockIdx.x / (N_ / P);
    int p0 = (blockIdx.x % (N_ / P)) * P;

    if (t < ROWS) nidx[t] = idx[((size_t)(bb * N_ + p0 + t / K_)) * K_ + t % K_];
    __syncthreads();

    constexpr int CH = ROWS * (CIN / 4);
    for (int c = t; c < CH; c += 256) {
        int r = c / (CIN / 4), cc = c % (CIN / 4);
        const float4 vv = *(const float4*)&x[((size_t)(bb * N_ + nidx[r])) * CIN + 4 * cc];
        unsigned short h0, h1, h2, h3, l0, l1, l2, l3;
        bf16split(vv.x, h0, l0);
        bf16split(vv.y, h1, l1);
        bf16split(vv.z, h2, l2);
        bf16split(vv.w, h3, l3);
        uint2 uh, ul;
        uh.x = (unsigned)h0 | ((unsigned)h1 << 16);
        uh.y = (unsigned)h2 | ((unsigned)h3 << 16);
        ul.x = (unsigned)l0 | ((unsigned)l1 << 16);
        ul.y = (unsigned)l2 | ((unsigned)l3 << 16);
        *(uint2*)&Ahi[r * STR + 4 * cc] = uh;
        *(uint2*)&Alo[r * STR + 4 * cc] = ul;
    }
    __syncthreads();

    int lane = t & 63, wave = t >> 6, quad = lane >> 4, nl = lane & 15;

    f32x4 acc[MT][NTW];
#pragma unroll
    for (int mt = 0; mt < MT; ++mt)
#pragma unroll
        for (int n = 0; n < NTW; ++n) acc[mt][n] = (f32x4){0.f, 0.f, 0.f, 0.f};

#pragma unroll
    for (int kc = 0; kc < KC; ++kc) {
        short8 ah[MT], al[MT];
#pragma unroll
        for (int mt = 0; mt < MT; ++mt) {
            int off = (mt * 16 + nl) * STR + kc * 32 + quad * 8;
            ah[mt] = *(const short8*)&Ahi[off];
            al[mt] = *(const short8*)&Alo[off];
        }
#pragma unroll
        for (int ntw = 0; ntw < NTW; ++ntw) {
            int ntg = wave * NTW + ntw;
            const short8 bh = *(const short8*)&Wh[((size_t)(kc * NT + ntg) * 64 + lane) * 8];
            const short8 bl = *(const short8*)&Wl[((size_t)(kc * NT + ntg) * 64 + lane) * 8];
#pragma unroll
            for (int mt = 0; mt < MT; ++mt) {
                acc[mt][ntw] = __builtin_amdgcn_mfma_f32_16x16x32_bf16(ah[mt], bh, acc[mt][ntw], 0, 0, 0);
                acc[mt][ntw] = __builtin_amdgcn_mfma_f32_16x16x32_bf16(ah[mt], bl, acc[mt][ntw], 0, 0, 0);
                acc[mt][ntw] = __builtin_amdgcn_mfma_f32_16x16x32_bf16(al[mt], bh, acc[mt][ntw], 0, 0, 0);
            }
        }
    }

    // epilogue: per-point max over the 20 k-rows, + cterm, lrelu, store.
    // C/D: col = lane&15, row = mt*16 + quad*4 + reg.  4-reg groups never
    // cross a point boundary (20 % 4 == 0).
#pragma unroll
    for (int ntw = 0; ntw < NTW; ++ntw) {
        int ntg = wave * NTW + ntw;
        int col = ntg * 16 + nl;
        float ctv[P];
#pragma unroll
        for (int pp = 0; pp < P; ++pp)
            ctv[pp] = cterm[(size_t)(bb * N_ + p0 + pp) * COUT + col];
        float pmax[P];
#pragma unroll
        for (int pp = 0; pp < P; ++pp) pmax[pp] = -INFINITY;
#pragma unroll
        for (int mt = 0; mt < MT; ++mt) {
            f32x4 a4 = acc[mt][ntw];
            float m3 = fmaxf(fmaxf(a4.x, a4.y), fmaxf(a4.z, a4.w));
            int p = (mt * 4 + quad) / 5;  // row0/20
#pragma unroll
            for (int pp = 0; pp < P; ++pp)
                pmax[pp] = (p == pp) ? fmaxf(pmax[pp], m3) : pmax[pp];
        }
#pragma unroll
        for (int pp = 0; pp < P; ++pp) {
            float m = pmax[pp];
            m = fmaxf(m, __shfl_xor(m, 16));
            m = fmaxf(m, __shfl_xor(m, 32));
            float val = m + ctv[pp];
            val = (val >= 0.f) ? val : 0.2f * val;
            if (lane < 16) out[(size_t)(bb * N_ + p0 + pp) * COUT + col] = val;
        }
    }
}

// ---------------------------------------------------------------- fp32 edge conv (L1 only)
template <int CIN, int COUT, int OO>
__global__ __launch_bounds__(COUT / OO) void conv_kernel(
    const float* __restrict__ x, const int* __restrict__ idx,
    const float* __restrict__ wdT, const float* __restrict__ wcdT,
    const float* __restrict__ bias2, float* __restrict__ out) {
    constexpr int TH = COUT / OO;
    __shared__ __align__(16) float nb[K_][CIN];
    __shared__ float ctr[CIN];
    __shared__ int nidx[K_];
    int p = blockIdx.x;
    int bb = p >> 10;
    int t = threadIdx.x;
    if (t < K_) nidx[t] = idx[(size_t)p * K_ + t];
    for (int c = t; c < CIN; c += TH) ctr[c] = x[(size_t)p * CIN + c];
    __syncthreads();
    for (int e = t; e < K_ * CIN; e += TH) {
        int k = e / CIN, c = e % CIN;
        nb[k][c] = x[(size_t)(bb * N_ + nidx[k]) * CIN + c];
    }
    __syncthreads();

    float tacc[OO];
    float acc[OO][K_];
#pragma unroll
    for (int oo = 0; oo < OO; ++oo) {
        tacc[oo] = bias2[t + oo * TH];
#pragma unroll
        for (int k = 0; k < K_; ++k) acc[oo][k] = 0.f;
    }
    for (int i = 0; i < CIN; ++i) {
        float cv = ctr[i];
#pragma unroll
        for (int oo = 0; oo < OO; ++oo) tacc[oo] += wcdT[i * COUT + t + oo * TH] * cv;
    }
    for (int i = 0; i < CIN; ++i) {
        float w[OO];
#pragma unroll
        for (int oo = 0; oo < OO; ++oo) w[oo] = wdT[i * COUT + t + oo * TH];
#pragma unroll
        for (int k = 0; k < K_; ++k) {
            float nv = nb[k][i];
#pragma unroll
            for (int oo = 0; oo < OO; ++oo) acc[oo][k] += w[oo] * nv;
        }
    }
#pragma unroll
    for (int oo = 0; oo < OO; ++oo) {
        float mx = -INFINITY;
#pragma unroll
        for (int k = 0; k < K_; ++k) {
            float val = acc[oo][k] + tacc[oo];
            val = (val >= 0.f) ? val : 0.2f * val;
            mx = fmaxf(mx, val);
        }
        out[(size_t)p * COUT + t + oo * TH] = mx;
    }
}

// ---------------------------------------------------------------- global max pool
template <int C>
__global__ __launch_bounds__(256) void pool_kernel(const float* __restrict__ h,
                                                   float* __restrict__ f, int off) {
    __shared__ float red[4][64];
    int bb = blockIdx.x / (C / 64);
    int c0 = (blockIdx.x % (C / 64)) * 64;
    int lane = threadIdx.x & 63, sl = threadIdx.x >> 6;
    int c = c0 + lane;
    const float* hb = h + (size_t)bb * N_ * C;
    float mx = -INFINITY;
    for (int n = sl * 256; n < sl * 256 + 256; ++n) mx = fmaxf(mx, hb[(size_t)n * C + c]);
    red[sl][lane] = mx;
    __syncthreads();
    if (sl == 0) {
        mx = fmaxf(fmaxf(red[0][lane], red[1][lane]), fmaxf(red[2][lane], red[3][lane]));
        f[bb * 384 + off + c] = mx;
    }
}

// ---------------------------------------------------------------- FC tail
__global__ __launch_bounds__(128) void fc_tail(
    const float* __restrict__ f, const float* __restrict__ f1w,
    const float* __restrict__ f1b, const float* __restrict__ n1g,
    const float* __restrict__ n1b, const float* __restrict__ n1m,
    const float* __restrict__ n1v, const float* __restrict__ f2w,
    const float* __restrict__ f2b, const float* __restrict__ n2g,
    const float* __restrict__ n2b, const float* __restrict__ n2m,
    const float* __restrict__ n2v, const float* __restrict__ f3w,
    const float* __restrict__ f3b, float* __restrict__ out) {
    __shared__ float fb[384];
    __shared__ float s1[128];
    __shared__ float s2[16];
    int bb = blockIdx.x, t = threadIdx.x;
    for (int j = t; j < 384; j += 128) fb[j] = f[bb * 384 + j];
    __syncthreads();
    float a = f1b[t];
    for (int j = 0; j < 384; ++j) a += f1w[t * 384 + j] * fb[j];
    a = (a - n1m[t]) * (n1g[t] / sqrtf(n1v[t] + EPS_)) + n1b[t];
    s1[t] = fmaxf(a, 0.f);
    __syncthreads();
    if (t < 16) {
        float a2 = f2b[t];
        for (int j = 0; j < 128; ++j) a2 += f2w[t * 128 + j] * s1[j];
        a2 = (a2 - n2m[t]) * (n2g[t] / sqrtf(n2v[t] + EPS_)) + n2b[t];
        s2[t] = fmaxf(a2, 0.f);
    }
    __syncthreads();
    if (t == 0) {
        float a3 = f3b[0];
        for (int j = 0; j < 16; ++j) a3 += f3w[j] * s2[j];
        out[bb] = a3;
    }
}

// ---------------------------------------------------------------- launch
extern "C" void kernel_launch(void* const* d_in, const int* in_sizes, int n_in,
                              void* d_out, int out_size, void* d_ws, size_t ws_size,
                              hipStream_t stream) {
    const float* x = (const float*)d_in[0];
    const float* cw[4] = {(const float*)d_in[1], (const float*)d_in[6],
                          (const float*)d_in[11], (const float*)d_in[16]};
    const float* cg[4] = {(const float*)d_in[2], (const float*)d_in[7],
                          (const float*)d_in[12], (const float*)d_in[17]};
    const float* cb[4] = {(const float*)d_in[3], (const float*)d_in[8],
                          (const float*)d_in[13], (const float*)d_in[18]};
    const float* cm[4] = {(const float*)d_in[4], (const float*)d_in[9],
                          (const float*)d_in[14], (const float*)d_in[19]};
    const float* cv[4] = {(const float*)d_in[5], (const float*)d_in[10],
                          (const float*)d_in[15], (const float*)d_in[20]};
    const float* f1w = (const float*)d_in[21];
    const float* f1b = (const float*)d_in[22];
    const float* n1g = (const float*)d_in[23];
    const float* n1b = (const float*)d_in[24];
    const float* n1m = (const float*)d_in[25];
    const float* n1v = (const float*)d_in[26];
    const float* f2w = (const float*)d_in[27];
    const float* f2b = (const float*)d_in[28];
    const float* n2g = (const float*)d_in[29];
    const float* n2b = (const float*)d_in[30];
    const float* n2m = (const float*)d_in[31];
    const float* n2v = (const float*)d_in[32];
    const float* f3w = (const float*)d_in[33];
    const float* f3b = (const float*)d_in[34];
    float* out = (float*)d_out;

    char* ws = (char*)d_ws;
    size_t off = 0;
    auto alloc = [&](size_t bytes) {
        void* p = ws + off;
        off += (bytes + 255) & ~(size_t)255;
        return p;
    };
    float* sq = (float*)alloc(B_ * N_ * 4);
    int* idx = (int*)alloc((size_t)B_ * N_ * K_ * 4);
    float* h1 = (float*)alloc((size_t)B_ * N_ * 64 * 4);
    float* h2 = (float*)alloc((size_t)B_ * N_ * 64 * 4);
    float* h3 = (float*)alloc((size_t)B_ * N_ * 128 * 4);
    float* h4 = (float*)alloc((size_t)B_ * N_ * 256 * 4);
    float* wd = (float*)alloc(128 * 256 * 4);
    float* wcd = (float*)alloc(128 * 256 * 4);
    float* b2 = (float*)alloc(256 * 4);
    float* f = (float*)alloc(B_ * 384 * 4);
    float* xT = (float*)alloc((size_t)B_ * 3 * N_ * 4);
    float* hT = (float*)alloc((size_t)B_ * 128 * N_ * 4);
    unsigned short* Wh = (unsigned short*)alloc(128 * 256 * 2);
    unsigned short* Wl = (unsigned short*)alloc(128 * 256 * 2);
    float* cterm = (float*)alloc((size_t)B_ * N_ * 256 * 4);
    (void)ws_size; (void)in_sizes; (void)n_in; (void)out_size;

    const int KB = B_ * (N_ / 8);

    // ---- layer 1: 3 -> 64 (fp32)
    xpose0_kernel<<<(B_ * N_) / 256, 256, 0, stream>>>(x, xT, sq);
    knn_kernel<3><<<KB, 256, 0, stream>>>(xT, x, sq, idx);
    prep_kernel<3, 64><<<1, 256, 0, stream>>>(cw[0], cg[0], cb[0], cm[0], cv[0], wd, wcd, b2);
    conv_kernel<3, 64, 1><<<B_ * N_, 64, 0, stream>>>(x, idx, wd, wcd, b2, h1);

    // ---- layer 2: 64 -> 64 (MFMA)
    sqk_kernel<64><<<(B_ * N_) / 256, 256, 0, stream>>>(h1, sq);
    tr_kernel<64><<<dim3(N_ / 64, 1, B_), 256, 0, stream>>>(h1, hT);
    knn_kernel<64><<<KB, 256, 0, stream>>>(hT, h1, sq, idx);
    prep_mfma<64, 64><<<16, 256, 0, stream>>>(cw[1], cg[1], cb[1], cm[1], cv[1], Wh, Wl, wcd, b2);
    cterm_kernel<64, 64, 8><<<B_ * N_ / 8, 64, 0, stream>>>(h1, wcd, b2, cterm);
    convm_kernel<64, 64, 8><<<B_ * N_ / 8, 256, 0, stream>>>(h1, idx, Wh, Wl, cterm, h2);

    // ---- layer 3: 64 -> 128 (MFMA)
    sqk_kernel<64><<<(B_ * N_) / 256, 256, 0, stream>>>(h2, sq);
    tr_kernel<64><<<dim3(N_ / 64, 1, B_), 256, 0, stream>>>(h2, hT);
    knn_kernel<64><<<KB, 256, 0, stream>>>(hT, h2, sq, idx);
    prep_mfma<64, 128><<<32, 256, 0, stream>>>(cw[2], cg[2], cb[2], cm[2], cv[2], Wh, Wl, wcd, b2);
    cterm_kernel<64, 128, 8><<<B_ * N_ / 8, 128, 0, stream>>>(h2, wcd, b2, cterm);
    convm_kernel<64, 128, 8><<<B_ * N_ / 8, 256, 0, stream>>>(h2, idx, Wh, Wl, cterm, h3);

    // ---- layer 4: 128 -> 256 (MFMA)
    sqk_kernel<128><<<(B_ * N_) / 256, 256, 0, stream>>>(h3, sq);
    tr_kernel<128><<<dim3(N_ / 64, 2, B_), 256, 0, stream>>>(h3, hT);
    knn_kernel<128><<<KB, 256, 0, stream>>>(hT, h3, sq, idx);
    prep_mfma<128, 256><<<128, 256, 0, stream>>>(cw[3], cg[3], cb[3], cm[3], cv[3], Wh, Wl, wcd, b2);
    cterm_kernel<128, 256, 8><<<B_ * N_ / 8, 256, 0, stream>>>(h3, wcd, b2, cterm);
    convm_kernel<128, 256, 4><<<B_ * N_ / 4, 256, 0, stream>>>(h3, idx, Wh, Wl, cterm, h4);

    // ---- pooling + FC tail
    pool_kernel<128><<<B_ * 2, 256, 0, stream>>>(h3, f, 0);
    pool_kernel<256><<<B_ * 4, 256, 0, stream>>>(h4, f, 128);
    fc_tail<<<B_, 128, 0, stream>>>(f, f1w, f1b, n1g, n1b, n1m, n1v, f2w, f2b, n2g, n2b,
                                    n2m, n2v, f3w, f3b, out);
}

// Round 4
// 610.916 us; speedup vs baseline: 3.0120x; 1.2001x over previous
//
#include <hip/hip_runtime.h>
#include <math.h>

constexpr int B_ = 8;
constexpr int N_ = 1024;
constexpr int K_ = 20;
constexpr float EPS_ = 1e-5f;

typedef __attribute__((ext_vector_type(8))) short short8;
typedef __attribute__((ext_vector_type(4))) float f32x4;
typedef unsigned long long u64;

// hi/lo bf16 split (RNE both halves)
__device__ __forceinline__ void bf16split(float x, unsigned short& h, unsigned short& l) {
    unsigned u = __float_as_uint(x);
    unsigned rh = (u + 0x7FFFu + ((u >> 16) & 1u)) >> 16;
    h = (unsigned short)rh;
    float lof = x - __uint_as_float(rh << 16);
    unsigned ul = __float_as_uint(lof);
    l = (unsigned short)((ul + 0x7FFFu + ((ul >> 16) & 1u)) >> 16);
}

// ---------------------------------------------------------------- layer-1 transpose + sq
__global__ __launch_bounds__(256) void xpose0_kernel(const float* __restrict__ x,
                                                     float* __restrict__ xT,
                                                     float* __restrict__ sq) {
    int t = blockIdx.x * 256 + threadIdx.x;
    if (t >= B_ * N_) return;
    int b = t >> 10, n = t & 1023;
    float a = x[3 * t], c = x[3 * t + 1], d = x[3 * t + 2];
    xT[((size_t)b * 3 + 0) * N_ + n] = a;
    xT[((size_t)b * 3 + 1) * N_ + n] = c;
    xT[((size_t)b * 3 + 2) * N_ + n] = d;
    sq[t] = a * a + c * c + d * d;
}

// ---------------------------------------------------------------- sq kernel
template <int C>
__global__ __launch_bounds__(256) void sqk_kernel(const float* __restrict__ h,
                                                  float* __restrict__ sq) {
    int p = blockIdx.x * 256 + threadIdx.x;
    if (p >= B_ * N_) return;
    const float4* r = (const float4*)(h + (size_t)p * C);
    float s = 0.f;
#pragma unroll
    for (int i = 0; i < C / 4; ++i) {
        float4 v = r[i];
        s += v.x * v.x + v.y * v.y + v.z * v.z + v.w * v.w;
    }
    sq[p] = s;
}

// ---------------------------------------------------------------- tiled transpose
template <int C>
__global__ __launch_bounds__(256) void tr_kernel(const float* __restrict__ h,
                                                 float* __restrict__ hT) {
    __shared__ float tile[64][65];
    int n0 = blockIdx.x * 64, c0 = blockIdx.y * 64, b = blockIdx.z;
    const float* hb = h + (size_t)b * N_ * C;
    float* hTb = hT + (size_t)b * C * N_;
    int j = threadIdx.x & 63, i4 = threadIdx.x >> 6;
#pragma unroll
    for (int ii = 0; ii < 16; ++ii)
        tile[i4 * 16 + ii][j] = hb[(size_t)(n0 + i4 * 16 + ii) * C + c0 + j];
    __syncthreads();
#pragma unroll
    for (int ii = 0; ii < 16; ++ii)
        hTb[(size_t)(c0 + i4 * 16 + ii) * N_ + n0 + j] = tile[j][i4 * 16 + ii];
}

// ---------------------------------------------------------------- knn kernel
__device__ __forceinline__ unsigned int fkey(float f) {
    unsigned int u = __float_as_uint(f);
    return (u & 0x80000000u) ? ~u : (u | 0x80000000u);
}

__device__ __forceinline__ u64 tree16(const u64* v) {
    u64 t0[8];
#pragma unroll
    for (int s = 0; s < 8; ++s) t0[s] = v[2 * s] > v[2 * s + 1] ? v[2 * s] : v[2 * s + 1];
#pragma unroll
    for (int s = 0; s < 4; ++s) t0[s] = t0[2 * s] > t0[2 * s + 1] ? t0[2 * s] : t0[2 * s + 1];
    t0[0] = t0[0] > t0[1] ? t0[0] : t0[1];
    t0[2] = t0[2] > t0[3] ? t0[2] : t0[3];
    return t0[0] > t0[2] ? t0[0] : t0[2];
}

// Phase A: column-split distance compute (thread owns 4 cols, 8 rows in regs),
// result to LDS. Phase B: per-wave 2-row interleaved top-20 selection.
template <int CIN>
__global__ __launch_bounds__(256) void knn_kernel(const float* __restrict__ xT,
                                                  const float* __restrict__ xrow,
                                                  const float* __restrict__ sq,
                                                  int* __restrict__ idx) {
    constexpr int ROWS = 8;
    __shared__ float dist[ROWS][N_];
    __shared__ float ctr[ROWS][CIN];
    __shared__ float sqr8[ROWS];
    int t = threadIdx.x;
    int bb = blockIdx.x / (N_ / ROWS);
    int r0 = (blockIdx.x % (N_ / ROWS)) * ROWS;
    const float* xtb = xT + (size_t)bb * CIN * N_;

    for (int e = t; e < ROWS * CIN; e += 256)
        ((float*)ctr)[e] = xrow[(size_t)(bb * N_ + r0) * CIN + e];
    if (t < ROWS) sqr8[t] = sq[bb * N_ + r0 + t];
    __syncthreads();

    // ---- phase A: distances for this thread's 4 columns
    {
        int c0 = t * 4;
        float4 sc = *(const float4*)&sq[bb * N_ + c0];
        float acc[ROWS][4];
#pragma unroll
        for (int r = 0; r < ROWS; ++r)
#pragma unroll
            for (int i = 0; i < 4; ++i) acc[r][i] = 0.f;

#pragma unroll 4
        for (int ci = 0; ci < CIN; ++ci) {
            float4 xv = *(const float4*)&xtb[(size_t)ci * N_ + c0];
#pragma unroll
            for (int r = 0; r < ROWS; ++r) {
                float p = ctr[r][ci];
                acc[r][0] = fmaf(p, xv.x, acc[r][0]);
                acc[r][1] = fmaf(p, xv.y, acc[r][1]);
                acc[r][2] = fmaf(p, xv.z, acc[r][2]);
                acc[r][3] = fmaf(p, xv.w, acc[r][3]);
            }
        }
#pragma unroll
        for (int r = 0; r < ROWS; ++r) {
            float sr = sqr8[r];
            float4 dv;
            dv.x = 2.f * acc[r][0] - sr - sc.x;
            dv.y = 2.f * acc[r][1] - sr - sc.y;
            dv.z = 2.f * acc[r][2] - sr - sc.z;
            dv.w = 2.f * acc[r][3] - sr - sc.w;
            *(float4*)&dist[r][c0] = dv;
        }
    }
    __syncthreads();

    // ---- phase B: wave w selects top-20 for rows 2w, 2w+1 (interleaved chains)
    int wave = t >> 6, lane = t & 63;
    int row0 = 2 * wave, row1 = 2 * wave + 1;

    u64 v0[16], v1[16];
#pragma unroll
    for (int j = 0; j < 16; ++j) {
        int c = lane + 64 * j;
        v0[j] = ((u64)fkey(dist[row0][c]) << 32) | (unsigned int)(~c);
        v1[j] = ((u64)fkey(dist[row1][c]) << 32) | (unsigned int)(~c);
    }
    int* op0 = idx + (size_t)(bb * N_ + r0 + row0) * K_;
    int* op1 = idx + (size_t)(bb * N_ + r0 + row1) * K_;

    for (int it = 0; it < K_; ++it) {
        u64 m0 = tree16(v0);
        u64 m1 = tree16(v1);
#pragma unroll
        for (int off = 32; off; off >>= 1) {
            u64 o0 = __shfl_xor(m0, off);
            u64 o1 = __shfl_xor(m1, off);
            m0 = o0 > m0 ? o0 : m0;
            m1 = o1 > m1 ? o1 : m1;
        }
        if (lane == 0) {
            op0[it] = (int)(~(unsigned int)m0);
            op1[it] = (int)(~(unsigned int)m1);
        }
#pragma unroll
        for (int j = 0; j < 16; ++j) {
            v0[j] = (v0[j] == m0) ? 0ull : v0[j];
            v1[j] = (v1[j] == m1) ? 0ull : v1[j];
        }
    }
}

// ---------------------------------------------------------------- fp32 weight prep (L1)
template <int CIN, int COUT>
__global__ __launch_bounds__(256) void prep_kernel(const float* __restrict__ w,
                                                   const float* __restrict__ g,
                                                   const float* __restrict__ bb,
                                                   const float* __restrict__ m,
                                                   const float* __restrict__ v,
                                                   float* __restrict__ wdT,
                                                   float* __restrict__ wcdT,
                                                   float* __restrict__ bias2) {
    int e = blockIdx.x * 256 + threadIdx.x;
    if (e >= CIN * COUT) return;
    int o = e % COUT;
    int i = e / COUT;
    float a = g[o] / sqrtf(v[o] + EPS_);
    float wd = w[o * 2 * CIN + i];
    wdT[e] = a * wd;
    wcdT[e] = a * (w[o * 2 * CIN + CIN + i] - wd);
    if (i == 0) bias2[o] = bb[o] - m[o] * a;
}

// ---------------------------------------------------------------- MFMA weight prep
template <int CIN, int COUT>
__global__ __launch_bounds__(256) void prep_mfma(const float* __restrict__ w,
                                                 const float* __restrict__ g,
                                                 const float* __restrict__ bb,
                                                 const float* __restrict__ m,
                                                 const float* __restrict__ v,
                                                 unsigned short* __restrict__ Wh,
                                                 unsigned short* __restrict__ Wl,
                                                 float* __restrict__ wcdT,
                                                 float* __restrict__ bias2) {
    int e = blockIdx.x * 256 + threadIdx.x;
    if (e >= CIN * COUT) return;
    int n = e % COUT, k = e / COUT;
    float a = g[n] / sqrtf(v[n] + EPS_);
    float wdv = a * w[n * 2 * CIN + k];
    unsigned short h, l;
    bf16split(wdv, h, l);
    int kc = k >> 5, ko = k & 31, quad = ko >> 3, j = ko & 7;
    int nt = n >> 4, nl = n & 15;
    constexpr int NT = COUT / 16;
    size_t pos = ((size_t)(kc * NT + nt) * 64 + quad * 16 + nl) * 8 + j;
    Wh[pos] = h;
    Wl[pos] = l;
    wcdT[k * COUT + n] = a * (w[n * 2 * CIN + CIN + k] - w[n * 2 * CIN + k]);
    if (k == 0) bias2[n] = bb[n] - m[n] * a;
}

// ---------------------------------------------------------------- ctr-term (fp32)
template <int CIN, int COUT, int PP>
__global__ __launch_bounds__(COUT) void cterm_kernel(const float* __restrict__ x,
                                                     const float* __restrict__ wcdT,
                                                     const float* __restrict__ bias2,
                                                     float* __restrict__ ct) {
    __shared__ float ctr[PP][CIN];
    int p0 = blockIdx.x * PP;
    int t = threadIdx.x;
    for (int e = t; e < PP * CIN; e += COUT)
        ctr[e / CIN][e % CIN] = x[(size_t)p0 * CIN + e];
    __syncthreads();
    float acc[PP];
#pragma unroll
    for (int pp = 0; pp < PP; ++pp) acc[pp] = bias2[t];
    for (int i = 0; i < CIN; ++i) {
        float w = wcdT[i * COUT + t];
#pragma unroll
        for (int pp = 0; pp < PP; ++pp) acc[pp] = fmaf(w, ctr[pp][i], acc[pp]);
    }
#pragma unroll
    for (int pp = 0; pp < PP; ++pp) ct[(size_t)(p0 + pp) * COUT + t] = acc[pp];
}

// ---------------------------------------------------------------- MFMA edge conv
template <int CIN, int COUT, int P>
__global__ __launch_bounds__(256) void convm_kernel(const float* __restrict__ x,
                                                    const int* __restrict__ idx,
                                                    const unsigned short* __restrict__ Wh,
                                                    const unsigned short* __restrict__ Wl,
                                                    const float* __restrict__ cterm,
                                                    float* __restrict__ out) {
    constexpr int ROWS = P * K_;
    constexpr int MT = ROWS / 16;
    constexpr int NT = COUT / 16;
    constexpr int NTW = NT / 4;
    constexpr int KC = CIN / 32;
    constexpr int STR = CIN + 8;
    __shared__ unsigned short Ahi[ROWS * STR];
    __shared__ unsigned short Alo[ROWS * STR];
    __shared__ int nidx[ROWS];

    int t = threadIdx.x;
    int bb = blockIdx.x / (N_ / P);
    int p0 = (blockIdx.x % (N_ / P)) * P;

    if (t < ROWS) nidx[t] = idx[((size_t)(bb * N_ + p0 + t / K_)) * K_ + t % K_];
    __syncthreads();

    constexpr int CH = ROWS * (CIN / 4);
    for (int c = t; c < CH; c += 256) {
        int r = c / (CIN / 4), cc = c % (CIN / 4);
        const float4 vv = *(const float4*)&x[((size_t)(bb * N_ + nidx[r])) * CIN + 4 * cc];
        unsigned short h0, h1, h2, h3, l0, l1, l2, l3;
        bf16split(vv.x, h0, l0);
        bf16split(vv.y, h1, l1);
        bf16split(vv.z, h2, l2);
        bf16split(vv.w, h3, l3);
        uint2 uh, ul;
        uh.x = (unsigned)h0 | ((unsigned)h1 << 16);
        uh.y = (unsigned)h2 | ((unsigned)h3 << 16);
        ul.x = (unsigned)l0 | ((unsigned)l1 << 16);
        ul.y = (unsigned)l2 | ((unsigned)l3 << 16);
        *(uint2*)&Ahi[r * STR + 4 * cc] = uh;
        *(uint2*)&Alo[r * STR + 4 * cc] = ul;
    }
    __syncthreads();

    int lane = t & 63, wave = t >> 6, quad = lane >> 4, nl = lane & 15;

    f32x4 acc[MT][NTW];
#pragma unroll
    for (int mt = 0; mt < MT; ++mt)
#pragma unroll
        for (int n = 0; n < NTW; ++n) acc[mt][n] = (f32x4){0.f, 0.f, 0.f, 0.f};

#pragma unroll
    for (int kc = 0; kc < KC; ++kc) {
        short8 ah[MT], al[MT];
#pragma unroll
        for (int mt = 0; mt < MT; ++mt) {
            int off = (mt * 16 + nl) * STR + kc * 32 + quad * 8;
            ah[mt] = *(const short8*)&Ahi[off];
            al[mt] = *(const short8*)&Alo[off];
        }
#pragma unroll
        for (int ntw = 0; ntw < NTW; ++ntw) {
            int ntg = wave * NTW + ntw;
            const short8 bh = *(const short8*)&Wh[((size_t)(kc * NT + ntg) * 64 + lane) * 8];
            const short8 bl = *(const short8*)&Wl[((size_t)(kc * NT + ntg) * 64 + lane) * 8];
#pragma unroll
            for (int mt = 0; mt < MT; ++mt) {
                acc[mt][ntw] = __builtin_amdgcn_mfma_f32_16x16x32_bf16(ah[mt], bh, acc[mt][ntw], 0, 0, 0);
                acc[mt][ntw] = __builtin_amdgcn_mfma_f32_16x16x32_bf16(ah[mt], bl, acc[mt][ntw], 0, 0, 0);
                acc[mt][ntw] = __builtin_amdgcn_mfma_f32_16x16x32_bf16(al[mt], bh, acc[mt][ntw], 0, 0, 0);
            }
        }
    }

#pragma unroll
    for (int ntw = 0; ntw < NTW; ++ntw) {
        int ntg = wave * NTW + ntw;
        int col = ntg * 16 + nl;
        float ctv[P];
#pragma unroll
        for (int pp = 0; pp < P; ++pp)
            ctv[pp] = cterm[(size_t)(bb * N_ + p0 + pp) * COUT + col];
        float pmax[P];
#pragma unroll
        for (int pp = 0; pp < P; ++pp) pmax[pp] = -INFINITY;
#pragma unroll
        for (int mt = 0; mt < MT; ++mt) {
            f32x4 a4 = acc[mt][ntw];
            float m3 = fmaxf(fmaxf(a4.x, a4.y), fmaxf(a4.z, a4.w));
            int p = (mt * 4 + quad) / 5;
#pragma unroll
            for (int pp = 0; pp < P; ++pp)
                pmax[pp] = (p == pp) ? fmaxf(pmax[pp], m3) : pmax[pp];
        }
#pragma unroll
        for (int pp = 0; pp < P; ++pp) {
            float m = pmax[pp];
            m = fmaxf(m, __shfl_xor(m, 16));
            m = fmaxf(m, __shfl_xor(m, 32));
            float val = m + ctv[pp];
            val = (val >= 0.f) ? val : 0.2f * val;
            if (lane < 16) out[(size_t)(bb * N_ + p0 + pp) * COUT + col] = val;
        }
    }
}

// ---------------------------------------------------------------- fp32 edge conv (L1 only)
template <int CIN, int COUT, int OO>
__global__ __launch_bounds__(COUT / OO) void conv_kernel(
    const float* __restrict__ x, const int* __restrict__ idx,
    const float* __restrict__ wdT, const float* __restrict__ wcdT,
    const float* __restrict__ bias2, float* __restrict__ out) {
    constexpr int TH = COUT / OO;
    __shared__ __align__(16) float nb[K_][CIN];
    __shared__ float ctr[CIN];
    __shared__ int nidx[K_];
    int p = blockIdx.x;
    int bb = p >> 10;
    int t = threadIdx.x;
    if (t < K_) nidx[t] = idx[(size_t)p * K_ + t];
    for (int c = t; c < CIN; c += TH) ctr[c] = x[(size_t)p * CIN + c];
    __syncthreads();
    for (int e = t; e < K_ * CIN; e += TH) {
        int k = e / CIN, c = e % CIN;
        nb[k][c] = x[(size_t)(bb * N_ + nidx[k]) * CIN + c];
    }
    __syncthreads();

    float tacc[OO];
    float acc[OO][K_];
#pragma unroll
    for (int oo = 0; oo < OO; ++oo) {
        tacc[oo] = bias2[t + oo * TH];
#pragma unroll
        for (int k = 0; k < K_; ++k) acc[oo][k] = 0.f;
    }
    for (int i = 0; i < CIN; ++i) {
        float cv = ctr[i];
#pragma unroll
        for (int oo = 0; oo < OO; ++oo) tacc[oo] += wcdT[i * COUT + t + oo * TH] * cv;
    }
    for (int i = 0; i < CIN; ++i) {
        float w[OO];
#pragma unroll
        for (int oo = 0; oo < OO; ++oo) w[oo] = wdT[i * COUT + t + oo * TH];
#pragma unroll
        for (int k = 0; k < K_; ++k) {
            float nv = nb[k][i];
#pragma unroll
            for (int oo = 0; oo < OO; ++oo) acc[oo][k] += w[oo] * nv;
        }
    }
#pragma unroll
    for (int oo = 0; oo < OO; ++oo) {
        float mx = -INFINITY;
#pragma unroll
        for (int k = 0; k < K_; ++k) {
            float val = acc[oo][k] + tacc[oo];
            val = (val >= 0.f) ? val : 0.2f * val;
            mx = fmaxf(mx, val);
        }
        out[(size_t)p * COUT + t + oo * TH] = mx;
    }
}

// ---------------------------------------------------------------- global max pool
template <int C>
__global__ __launch_bounds__(256) void pool_kernel(const float* __restrict__ h,
                                                   float* __restrict__ f, int off) {
    __shared__ float red[4][64];
    int bb = blockIdx.x / (C / 64);
    int c0 = (blockIdx.x % (C / 64)) * 64;
    int lane = threadIdx.x & 63, sl = threadIdx.x >> 6;
    int c = c0 + lane;
    const float* hb = h + (size_t)bb * N_ * C;
    float mx = -INFINITY;
    for (int n = sl * 256; n < sl * 256 + 256; ++n) mx = fmaxf(mx, hb[(size_t)n * C + c]);
    red[sl][lane] = mx;
    __syncthreads();
    if (sl == 0) {
        mx = fmaxf(fmaxf(red[0][lane], red[1][lane]), fmaxf(red[2][lane], red[3][lane]));
        f[bb * 384 + off + c] = mx;
    }
}

// ---------------------------------------------------------------- FC tail
__global__ __launch_bounds__(128) void fc_tail(
    const float* __restrict__ f, const float* __restrict__ f1w,
    const float* __restrict__ f1b, const float* __restrict__ n1g,
    const float* __restrict__ n1b, const float* __restrict__ n1m,
    const float* __restrict__ n1v, const float* __restrict__ f2w,
    const float* __restrict__ f2b, const float* __restrict__ n2g,
    const float* __restrict__ n2b, const float* __restrict__ n2m,
    const float* __restrict__ n2v, const float* __restrict__ f3w,
    const float* __restrict__ f3b, float* __restrict__ out) {
    __shared__ float fb[384];
    __shared__ float s1[128];
    __shared__ float s2[16];
    int bb = blockIdx.x, t = threadIdx.x;
    for (int j = t; j < 384; j += 128) fb[j] = f[bb * 384 + j];
    __syncthreads();
    float a = f1b[t];
    for (int j = 0; j < 384; ++j) a += f1w[t * 384 + j] * fb[j];
    a = (a - n1m[t]) * (n1g[t] / sqrtf(n1v[t] + EPS_)) + n1b[t];
    s1[t] = fmaxf(a, 0.f);
    __syncthreads();
    if (t < 16) {
        float a2 = f2b[t];
        for (int j = 0; j < 128; ++j) a2 += f2w[t * 128 + j] * s1[j];
        a2 = (a2 - n2m[t]) * (n2g[t] / sqrtf(n2v[t] + EPS_)) + n2b[t];
        s2[t] = fmaxf(a2, 0.f);
    }
    __syncthreads();
    if (t == 0) {
        float a3 = f3b[0];
        for (int j = 0; j < 16; ++j) a3 += f3w[j] * s2[j];
        out[bb] = a3;
    }
}

// ---------------------------------------------------------------- launch
extern "C" void kernel_launch(void* const* d_in, const int* in_sizes, int n_in,
                              void* d_out, int out_size, void* d_ws, size_t ws_size,
                              hipStream_t stream) {
    const float* x = (const float*)d_in[0];
    const float* cw[4] = {(const float*)d_in[1], (const float*)d_in[6],
                          (const float*)d_in[11], (const float*)d_in[16]};
    const float* cg[4] = {(const float*)d_in[2], (const float*)d_in[7],
                          (const float*)d_in[12], (const float*)d_in[17]};
    const float* cb[4] = {(const float*)d_in[3], (const float*)d_in[8],
                          (const float*)d_in[13], (const float*)d_in[18]};
    const float* cm[4] = {(const float*)d_in[4], (const float*)d_in[9],
                          (const float*)d_in[14], (const float*)d_in[19]};
    const float* cv[4] = {(const float*)d_in[5], (const float*)d_in[10],
                          (const float*)d_in[15], (const float*)d_in[20]};
    const float* f1w = (const float*)d_in[21];
    const float* f1b = (const float*)d_in[22];
    const float* n1g = (const float*)d_in[23];
    const float* n1b = (const float*)d_in[24];
    const float* n1m = (const float*)d_in[25];
    const float* n1v = (const float*)d_in[26];
    const float* f2w = (const float*)d_in[27];
    const float* f2b = (const float*)d_in[28];
    const float* n2g = (const float*)d_in[29];
    const float* n2b = (const float*)d_in[30];
    const float* n2m = (const float*)d_in[31];
    const float* n2v = (const float*)d_in[32];
    const float* f3w = (const float*)d_in[33];
    const float* f3b = (const float*)d_in[34];
    float* out = (float*)d_out;

    char* ws = (char*)d_ws;
    size_t off = 0;
    auto alloc = [&](size_t bytes) {
        void* p = ws + off;
        off += (bytes + 255) & ~(size_t)255;
        return p;
    };
    float* sq = (float*)alloc(B_ * N_ * 4);
    int* idx = (int*)alloc((size_t)B_ * N_ * K_ * 4);
    float* h1 = (float*)alloc((size_t)B_ * N_ * 64 * 4);
    float* h2 = (float*)alloc((size_t)B_ * N_ * 64 * 4);
    float* h3 = (float*)alloc((size_t)B_ * N_ * 128 * 4);
    float* h4 = (float*)alloc((size_t)B_ * N_ * 256 * 4);
    float* wd = (float*)alloc(128 * 256 * 4);
    float* wcd = (float*)alloc(128 * 256 * 4);
    float* b2 = (float*)alloc(256 * 4);
    float* f = (float*)alloc(B_ * 384 * 4);
    float* xT = (float*)alloc((size_t)B_ * 3 * N_ * 4);
    float* hT = (float*)alloc((size_t)B_ * 128 * N_ * 4);
    unsigned short* Wh = (unsigned short*)alloc(128 * 256 * 2);
    unsigned short* Wl = (unsigned short*)alloc(128 * 256 * 2);
    float* cterm = (float*)alloc((size_t)B_ * N_ * 256 * 4);
    (void)ws_size; (void)in_sizes; (void)n_in; (void)out_size;

    const int KB = B_ * (N_ / 8);

    // ---- layer 1: 3 -> 64 (fp32)
    xpose0_kernel<<<(B_ * N_) / 256, 256, 0, stream>>>(x, xT, sq);
    knn_kernel<3><<<KB, 256, 0, stream>>>(xT, x, sq, idx);
    prep_kernel<3, 64><<<1, 256, 0, stream>>>(cw[0], cg[0], cb[0], cm[0], cv[0], wd, wcd, b2);
    conv_kernel<3, 64, 1><<<B_ * N_, 64, 0, stream>>>(x, idx, wd, wcd, b2, h1);

    // ---- layer 2: 64 -> 64 (MFMA)
    sqk_kernel<64><<<(B_ * N_) / 256, 256, 0, stream>>>(h1, sq);
    tr_kernel<64><<<dim3(N_ / 64, 1, B_), 256, 0, stream>>>(h1, hT);
    knn_kernel<64><<<KB, 256, 0, stream>>>(hT, h1, sq, idx);
    prep_mfma<64, 64><<<16, 256, 0, stream>>>(cw[1], cg[1], cb[1], cm[1], cv[1], Wh, Wl, wcd, b2);
    cterm_kernel<64, 64, 8><<<B_ * N_ / 8, 64, 0, stream>>>(h1, wcd, b2, cterm);
    convm_kernel<64, 64, 8><<<B_ * N_ / 8, 256, 0, stream>>>(h1, idx, Wh, Wl, cterm, h2);

    // ---- layer 3: 64 -> 128 (MFMA)
    sqk_kernel<64><<<(B_ * N_) / 256, 256, 0, stream>>>(h2, sq);
    tr_kernel<64><<<dim3(N_ / 64, 1, B_), 256, 0, stream>>>(h2, hT);
    knn_kernel<64><<<KB, 256, 0, stream>>>(hT, h2, sq, idx);
    prep_mfma<64, 128><<<32, 256, 0, stream>>>(cw[2], cg[2], cb[2], cm[2], cv[2], Wh, Wl, wcd, b2);
    cterm_kernel<64, 128, 8><<<B_ * N_ / 8, 128, 0, stream>>>(h2, wcd, b2, cterm);
    convm_kernel<64, 128, 8><<<B_ * N_ / 8, 256, 0, stream>>>(h2, idx, Wh, Wl, cterm, h3);

    // ---- layer 4: 128 -> 256 (MFMA)
    sqk_kernel<128><<<(B_ * N_) / 256, 256, 0, stream>>>(h3, sq);
    tr_kernel<128><<<dim3(N_ / 64, 2, B_), 256, 0, stream>>>(h3, hT);
    knn_kernel<128><<<KB, 256, 0, stream>>>(hT, h3, sq, idx);
    prep_mfma<128, 256><<<128, 256, 0, stream>>>(cw[3], cg[3], cb[3], cm[3], cv[3], Wh, Wl, wcd, b2);
    cterm_kernel<128, 256, 8><<<B_ * N_ / 8, 256, 0, stream>>>(h3, wcd, b2, cterm);
    convm_kernel<128, 256, 4><<<B_ * N_ / 4, 256, 0, stream>>>(h3, idx, Wh, Wl, cterm, h4);

    // ---- pooling + FC tail
    pool_kernel<128><<<B_ * 2, 256, 0, stream>>>(h3, f, 0);
    pool_kernel<256><<<B_ * 4, 256, 0, stream>>>(h4, f, 128);
    fc_tail<<<B_, 128, 0, stream>>>(f, f1w, f1b, n1g, n1b, n1m, n1v, f2w, f2b, n2g, n2b,
                                    n2m, n2v, f3w, f3b, out);
}